// Round 12
// baseline (779.641 us; speedup 1.0000x reference)
//
#include <hip/hip_runtime.h>

#define H    128
#define NMQ  50000
#define NSQ  50000
#define NE   600000
#define NEL  200000
#define FIN  768
#define NLAYERS 4
#define NBLK (NSQ / 16)   // 16-row tiles per side

typedef __attribute__((ext_vector_type(8))) short bf16x8;
typedef __attribute__((ext_vector_type(4))) float f32x4;

__device__ inline ushort f2b(float f) {
  unsigned u = __float_as_uint(f);
  u = (u + 0x7FFFu + ((u >> 16) & 1u)) >> 16;
  return (ushort)u;
}
__device__ inline float b2f(ushort h) { return __uint_as_float((unsigned)h << 16); }

// ---------------- fp32 -> bf16 convert (n divisible by 4) ----------------
__global__ void cvt_bf16(const float* __restrict__ in, ushort* __restrict__ out, int n4) {
  int i = blockIdx.x * blockDim.x + threadIdx.x;
  if (i >= n4) return;
  float4 v = ((const float4*)in)[i];
  ushort4 o;
  o.x = f2b(v.x); o.y = f2b(v.y); o.z = f2b(v.z); o.w = f2b(v.w);
  ((ushort4*)out)[i] = o;
}

// ---------------- batched weight convert: 5 tensors via blockIdx.y ----------------
__global__ void cvt_w5(const float* __restrict__ linW,
                       const float* __restrict__ Wls, const float* __restrict__ Wrs,
                       const float* __restrict__ Wlm, const float* __restrict__ Wrm,
                       ushort* olinW, ushort* oWls, ushort* oWrs, ushort* oWlm, ushort* oWrm) {
  const float* in; ushort* out; int n4;
  switch (blockIdx.y) {
    case 0: in = linW; out = olinW; n4 = H * FIN / 4; break;
    case 1: in = Wls;  out = oWls;  n4 = NLAYERS * H * H / 4; break;
    case 2: in = Wrs;  out = oWrs;  n4 = NLAYERS * H * H / 4; break;
    case 3: in = Wlm;  out = oWlm;  n4 = NLAYERS * H * H / 4; break;
    default: in = Wrm; out = oWrm;  n4 = NLAYERS * H * H / 4; break;
  }
  int i = blockIdx.x * blockDim.x + threadIdx.x;
  if (i >= n4) return;
  float4 v = ((const float4*)in)[i];
  ushort4 o;
  o.x = f2b(v.x); o.y = f2b(v.y); o.z = f2b(v.z); o.w = f2b(v.w);
  ((ushort4*)out)[i] = o;
}

// ---------------- encoder: x_sq = bf16(sq_x @ lin_W^T + lin_b + movie_emb) ----------------
// One wave per 16 rows (r6 known-best form: 125 us).
__global__ __launch_bounds__(64) void encoder_mfma(
    const float* __restrict__ A, const ushort* __restrict__ Wb,
    const float* __restrict__ bias, const float* __restrict__ memb,
    ushort* __restrict__ C)
{
  int lane = threadIdx.x;
  int rowbase = blockIdx.x * 16;
  int t = lane >> 4, fr = lane & 15;
  f32x4 acc[8];
  #pragma unroll
  for (int c = 0; c < 8; ++c)
    #pragma unroll
    for (int q = 0; q < 4; ++q) acc[c][q] = 0.f;

  int arow = rowbase + fr;           // 50000 % 16 == 0
  const float* Abase = A + (long)arow * FIN + t * 8;

  for (int k0 = 0; k0 < FIN; k0 += 32) {
    bf16x8 af, bfm[8];
    {
      const float* p = Abase + k0;
      float4 v0 = *(const float4*)p;
      float4 v1 = *(const float4*)(p + 4);
      ushort tmp[8];
      tmp[0] = f2b(v0.x); tmp[1] = f2b(v0.y); tmp[2] = f2b(v0.z); tmp[3] = f2b(v0.w);
      tmp[4] = f2b(v1.x); tmp[5] = f2b(v1.y); tmp[6] = f2b(v1.z); tmp[7] = f2b(v1.w);
      af = *(bf16x8*)tmp;
    }
    #pragma unroll
    for (int cc = 0; cc < 8; ++cc) {
      int col = cc * 16 + fr;
      bfm[cc] = *(const bf16x8*)(Wb + (long)col * FIN + k0 + t * 8);
    }
    #pragma unroll
    for (int cc = 0; cc < 8; ++cc)
      acc[cc] = __builtin_amdgcn_mfma_f32_16x16x32_bf16(af, bfm[cc], acc[cc], 0, 0, 0);
  }
  #pragma unroll
  for (int cc = 0; cc < 8; ++cc)
    #pragma unroll
    for (int q = 0; q < 4; ++q) {
      int row = rowbase + t * 4 + q;
      int col = cc * 16 + fr;
      float v = acc[cc][q] + bias[col] + memb[(long)row * H + col];
      C[(long)row * H + col] = f2b(v);
    }
}

// ---------------- merged both-sides fused SpMM-mean + SAGE GEMM ----------------
// 4 waves per block. Phase 1: wave w gathers rows [4w, 4w+4) of the 16-row tile
// (3x the resident gather streams vs 1-wave blocks). Barrier. Phase 2: wave w
// computes output cols [32w, 32w+32) for all 16 rows.
__global__ __launch_bounds__(256) void fused_layer2(
    const ushort* __restrict__ xmq, const ushort* __restrict__ xsq,
    const int* __restrict__ offs_f, const int* __restrict__ csr_f,
    const int* __restrict__ offs_r, const int* __restrict__ csr_r,
    const ushort* __restrict__ Wls, const ushort* __restrict__ Wrs,
    const float* __restrict__ bls,
    const ushort* __restrict__ Wlm, const ushort* __restrict__ Wrm,
    const float* __restrict__ blm,
    ushort* __restrict__ nsq, ushort* __restrict__ nmq, int relu)
{
  __shared__ ushort mtile[16 * 128];  // 4 KB, 16B-slot XOR swizzle
  int side = blockIdx.x >= NBLK;
  int bidx = side ? blockIdx.x - NBLK : blockIdx.x;
  const ushort* xg   = side ? xsq    : xmq;
  const ushort* xs   = side ? xmq    : xsq;
  const int*    offs = side ? offs_r : offs_f;
  const int*    csr  = side ? csr_r  : csr_f;
  const ushort* Wl   = side ? Wlm    : Wls;
  const ushort* Wr   = side ? Wrm    : Wrs;
  const float*  bias = side ? blm    : bls;
  ushort*       Cout = side ? nmq    : nsq;

  int tid = threadIdx.x, wave = tid >> 6, lane = tid & 63;
  int rowbase = bidx * 16;
  const unsigned* X = (const unsigned*)xg;

  // ---- phase 1: means, 4 rows per wave ----
  int wslot = lane >> 2;
  unsigned* mt32 = (unsigned*)mtile;
  for (int i4 = 0; i4 < 4; ++i4) {
    int i = wave * 4 + i4;
    int row = rowbase + i;
    int s = offs[row], e = offs[row + 1];
    float a0 = 0.f, a1 = 0.f;
    int j = s;
    for (; j + 8 <= e; j += 8) {
      long i0 = csr[j], i1 = csr[j+1], i2 = csr[j+2], i3 = csr[j+3];
      long i4_ = csr[j+4], i5 = csr[j+5], i6 = csr[j+6], i7 = csr[j+7];
      unsigned x0 = X[i0*64+lane], x1 = X[i1*64+lane], x2 = X[i2*64+lane], x3 = X[i3*64+lane];
      unsigned x4 = X[i4_*64+lane], x5 = X[i5*64+lane], x6 = X[i6*64+lane], x7 = X[i7*64+lane];
      a0 += b2f((ushort)(x0 & 0xffff)) + b2f((ushort)(x1 & 0xffff))
          + b2f((ushort)(x2 & 0xffff)) + b2f((ushort)(x3 & 0xffff))
          + b2f((ushort)(x4 & 0xffff)) + b2f((ushort)(x5 & 0xffff))
          + b2f((ushort)(x6 & 0xffff)) + b2f((ushort)(x7 & 0xffff));
      a1 += b2f((ushort)(x0 >> 16)) + b2f((ushort)(x1 >> 16))
          + b2f((ushort)(x2 >> 16)) + b2f((ushort)(x3 >> 16))
          + b2f((ushort)(x4 >> 16)) + b2f((ushort)(x5 >> 16))
          + b2f((ushort)(x6 >> 16)) + b2f((ushort)(x7 >> 16));
    }
    if (j + 4 <= e) {
      long i0 = csr[j], i1 = csr[j+1], i2 = csr[j+2], i3 = csr[j+3];
      unsigned x0 = X[i0*64+lane], x1 = X[i1*64+lane], x2 = X[i2*64+lane], x3 = X[i3*64+lane];
      a0 += b2f((ushort)(x0 & 0xffff)) + b2f((ushort)(x1 & 0xffff))
          + b2f((ushort)(x2 & 0xffff)) + b2f((ushort)(x3 & 0xffff));
      a1 += b2f((ushort)(x0 >> 16)) + b2f((ushort)(x1 >> 16))
          + b2f((ushort)(x2 >> 16)) + b2f((ushort)(x3 >> 16));
      j += 4;
    }
    for (; j < e; ++j) {
      unsigned x = X[(long)csr[j] * 64 + lane];
      a0 += b2f((ushort)(x & 0xffff));
      a1 += b2f((ushort)(x >> 16));
    }
    float inv = (e > s) ? 1.f / (float)(e - s) : 0.f;
    a0 *= inv; a1 *= inv;
    int sw = (wslot & 8) | ((wslot & 7) ^ (i & 7));
    mt32[i * 64 + sw * 4 + (lane & 3)] = (unsigned)f2b(a0) | ((unsigned)f2b(a1) << 16);
  }
  __syncthreads();

  // ---- phase 2: GEMM, wave w -> col-tiles {2w, 2w+1} ----
  int t = lane >> 4, fr = lane & 15;
  f32x4 acc[2];
  #pragma unroll
  for (int c = 0; c < 2; ++c)
    #pragma unroll
    for (int q = 0; q < 4; ++q) acc[c][q] = 0.f;

  // self-side A fragments (16 rows, L1/L2-hot: every wave reads the same 4 KB)
  int srow = rowbase + fr;
  // mean side (A from LDS) + self side, K = 128 each
  #pragma unroll
  for (int ks = 0; ks < 4; ++ks) {
    int slot = ks * 4 + t;
    int sw = (slot & 8) | ((slot & 7) ^ (fr & 7));
    bf16x8 af = *(const bf16x8*)&mtile[fr * 128 + sw * 8];
    bf16x8 bfm[2];
    #pragma unroll
    for (int cc = 0; cc < 2; ++cc) {
      int col = (wave * 2 + cc) * 16 + fr;
      bfm[cc] = *(const bf16x8*)(Wl + (long)col * H + slot * 8);
    }
    #pragma unroll
    for (int cc = 0; cc < 2; ++cc)
      acc[cc] = __builtin_amdgcn_mfma_f32_16x16x32_bf16(af, bfm[cc], acc[cc], 0, 0, 0);
  }
  #pragma unroll
  for (int ks = 0; ks < 4; ++ks) {
    int slot = ks * 4 + t;
    bf16x8 af = *(const bf16x8*)(xs + (long)srow * H + slot * 8);
    bf16x8 bfm[2];
    #pragma unroll
    for (int cc = 0; cc < 2; ++cc) {
      int col = (wave * 2 + cc) * 16 + fr;
      bfm[cc] = *(const bf16x8*)(Wr + (long)col * H + slot * 8);
    }
    #pragma unroll
    for (int cc = 0; cc < 2; ++cc)
      acc[cc] = __builtin_amdgcn_mfma_f32_16x16x32_bf16(af, bfm[cc], acc[cc], 0, 0, 0);
  }
  // epilogue
  #pragma unroll
  for (int cc = 0; cc < 2; ++cc)
    #pragma unroll
    for (int q = 0; q < 4; ++q) {
      int row = rowbase + t * 4 + q;
      int col = (wave * 2 + cc) * 16 + fr;
      float v = acc[cc][q] + bias[col];
      if (relu) v = fmaxf(v, 0.f);
      Cout[(long)row * H + col] = f2b(v);
    }
}

// ---------------- degree count ----------------
__global__ void deg_count(const int* __restrict__ eidx, int* __restrict__ df, int* __restrict__ dr) {
  int e = blockIdx.x * blockDim.x + threadIdx.x;
  if (e >= NE) return;
  atomicAdd(dr + eidx[e], 1);
  atomicAdd(df + eidx[NE + e], 1);
}

// ---------------- dual exclusive scan: block 0 -> forward, block 1 -> reverse ----------------
__global__ __launch_bounds__(1024) void exscan2(
    const int* __restrict__ degf, const int* __restrict__ degr,
    int* __restrict__ offf, int* __restrict__ offr)
{
  __shared__ int part[1024];
  const int* deg = blockIdx.x ? degr : degf;
  int* offs = blockIdx.x ? offr : offf;
  int n = blockIdx.x ? NMQ : NSQ;
  int t = threadIdx.x;
  int chunk = (n + 1023) >> 10;
  int beg = t * chunk, end = beg + chunk;
  if (end > n) end = n;
  int s = 0;
  for (int i = beg; i < end; ++i) s += deg[i];
  part[t] = s;
  __syncthreads();
  for (int offd = 1; offd < 1024; offd <<= 1) {
    int v = 0;
    if (t >= offd) v = part[t - offd];
    __syncthreads();
    part[t] += v;
    __syncthreads();
  }
  int run = (t == 0) ? 0 : part[t - 1];
  for (int i = beg; i < end; ++i) { offs[i] = run; run += deg[i]; }
  if (t == 1023) offs[n] = part[1023];
}

// ---------------- CSR fill ----------------
__global__ void csr_fill(const int* __restrict__ eidx,
                         const int* __restrict__ offs_f, const int* __restrict__ offs_r,
                         int* __restrict__ cur_f, int* __restrict__ cur_r,
                         int* __restrict__ csr_f, int* __restrict__ csr_r) {
  int e = blockIdx.x * blockDim.x + threadIdx.x;
  if (e >= NE) return;
  int s = eidx[e], d = eidx[NE + e];
  int p = atomicAdd(cur_f + d, 1); csr_f[offs_f[d] + p] = s;
  int q = atomicAdd(cur_r + s, 1); csr_r[offs_r[s] + q] = d;
}

// ---------------- classifier: one wave per label edge ----------------
__global__ __launch_bounds__(256) void edge_dot_b(
    const ushort* __restrict__ xmq, const ushort* __restrict__ xsq,
    const int* __restrict__ eli, float* __restrict__ out)
{
  int wid = (blockIdx.x << 2) + (threadIdx.x >> 6);
  int lane = threadIdx.x & 63;
  if (wid >= NEL) return;
  int a = eli[wid], b = eli[NEL + wid];
  unsigned xa = ((const unsigned*)xmq)[(long)a * 64 + lane];
  unsigned xb = ((const unsigned*)xsq)[(long)b * 64 + lane];
  float p = b2f((ushort)(xa & 0xffff)) * b2f((ushort)(xb & 0xffff))
          + b2f((ushort)(xa >> 16))    * b2f((ushort)(xb >> 16));
  #pragma unroll
  for (int off = 32; off; off >>= 1) p += __shfl_down(p, off, 64);
  if (lane == 0) out[wid] = p;
}

extern "C" void kernel_launch(void* const* d_in, const int* in_sizes, int n_in,
                              void* d_out, int out_size, void* d_ws, size_t ws_size,
                              hipStream_t stream) {
  (void)in_sizes; (void)n_in; (void)out_size; (void)ws_size;
  // d_in[0]=mq_node_id (arange, unused), d_in[1]=sq_node_id (arange, unused)
  const float* sq_x      = (const float*)d_in[2];
  const int*   eidx      = (const int*)d_in[3];
  const int*   eli       = (const int*)d_in[4];
  const float* user_emb  = (const float*)d_in[5];
  const float* movie_emb = (const float*)d_in[6];
  const float* lin_W     = (const float*)d_in[7];
  const float* lin_b     = (const float*)d_in[8];
  const float* Wl_s      = (const float*)d_in[9];
  const float* bl_s      = (const float*)d_in[10];
  const float* Wr_s      = (const float*)d_in[11];
  const float* Wl_m      = (const float*)d_in[12];
  const float* bl_m      = (const float*)d_in[13];
  const float* Wr_m      = (const float*)d_in[14];
  float* out = (float*)d_out;

  char* ws = (char*)d_ws;
  size_t off = 0;
  auto alloc = [&](size_t bytes) {
    char* p = ws + off;
    off += (bytes + 255) & ~(size_t)255;
    return p;
  };
  ushort* xmq_a = (ushort*)alloc((size_t)NMQ * H * 2);
  ushort* xmq_b = (ushort*)alloc((size_t)NMQ * H * 2);
  ushort* xsq_a = (ushort*)alloc((size_t)NSQ * H * 2);
  ushort* xsq_b = (ushort*)alloc((size_t)NSQ * H * 2);
  ushort* linWb = (ushort*)alloc((size_t)H * FIN * 2);
  ushort* Wlsb  = (ushort*)alloc((size_t)NLAYERS * H * H * 2);
  ushort* Wrsb  = (ushort*)alloc((size_t)NLAYERS * H * H * 2);
  ushort* Wlmb  = (ushort*)alloc((size_t)NLAYERS * H * H * 2);
  ushort* Wrmb  = (ushort*)alloc((size_t)NLAYERS * H * H * 2);
  int* deg_f  = (int*)alloc((size_t)NSQ * 4);
  int* deg_r  = (int*)alloc((size_t)NMQ * 4);
  int* cur_f  = (int*)alloc((size_t)NSQ * 4);
  int* cur_r  = (int*)alloc((size_t)NMQ * 4);
  int* offs_f = (int*)alloc((size_t)(NSQ + 1) * 4);
  int* offs_r = (int*)alloc((size_t)(NMQ + 1) * 4);
  int* csr_f  = (int*)alloc((size_t)NE * 4);
  int* csr_r  = (int*)alloc((size_t)NE * 4);

  hipMemsetAsync(deg_f, 0, (char*)offs_f - (char*)deg_f, stream);

  // conversions (2 launches: embeddings + batched weights)
  cvt_bf16<<<(NMQ * H / 4 + 255) / 256, 256, 0, stream>>>(user_emb, xmq_a, NMQ * H / 4);
  cvt_w5<<<dim3((H * FIN / 4 + 255) / 256, 5), 256, 0, stream>>>(
      lin_W, Wl_s, Wr_s, Wl_m, Wr_m, linWb, Wlsb, Wrsb, Wlmb, Wrmb);

  encoder_mfma<<<NSQ / 16, 64, 0, stream>>>(sq_x, linWb, lin_b, movie_emb, xsq_a);
  deg_count<<<(NE + 255) / 256, 256, 0, stream>>>(eidx, deg_f, deg_r);
  exscan2<<<2, 1024, 0, stream>>>(deg_f, deg_r, offs_f, offs_r);
  csr_fill<<<(NE + 255) / 256, 256, 0, stream>>>(eidx, offs_f, offs_r, cur_f, cur_r, csr_f, csr_r);

  ushort *cm = xmq_a, *cs = xsq_a, *nm = xmq_b, *ns = xsq_b;
  for (int l = 0; l < NLAYERS; ++l) {
    fused_layer2<<<2 * NBLK, 256, 0, stream>>>(cm, cs, offs_f, csr_f, offs_r, csr_r,
        Wlsb + (size_t)l * H * H, Wrsb + (size_t)l * H * H, bl_s + (size_t)l * H,
        Wlmb + (size_t)l * H * H, Wrmb + (size_t)l * H * H, bl_m + (size_t)l * H,
        ns, nm, l == 0);
    ushort* t;
    t = cm; cm = nm; nm = t;
    t = cs; cs = ns; ns = t;
  }
  edge_dot_b<<<(NEL + 3) / 4, 256, 0, stream>>>(cm, cs, eli, out);
}

// Round 14
// 763.585 us; speedup vs baseline: 1.0210x; 1.0210x over previous
//
#include <hip/hip_runtime.h>

#define H    128
#define NMQ  50000
#define NSQ  50000
#define NE   600000
#define NEL  200000
#define FIN  768
#define NLAYERS 4
#define NBLK (NSQ / 16)        // 16-row tiles per side
#define NGMAX 188000           // max groups per side: (NE + 3*N)/4 = 187500
#define PCMAX (NGMAX * 4)

typedef __attribute__((ext_vector_type(8))) short bf16x8;
typedef __attribute__((ext_vector_type(4))) float f32x4;

__device__ inline ushort f2b(float f) {
  unsigned u = __float_as_uint(f);
  u = (u + 0x7FFFu + ((u >> 16) & 1u)) >> 16;
  return (ushort)u;
}
__device__ inline float b2f(ushort h) { return __uint_as_float((unsigned)h << 16); }

// ---------------- fp32 -> bf16 convert ----------------
__global__ void cvt_bf16(const float* __restrict__ in, ushort* __restrict__ out, int n4) {
  int i = blockIdx.x * blockDim.x + threadIdx.x;
  if (i >= n4) return;
  float4 v = ((const float4*)in)[i];
  ushort4 o;
  o.x = f2b(v.x); o.y = f2b(v.y); o.z = f2b(v.z); o.w = f2b(v.w);
  ((ushort4*)out)[i] = o;
}

// ---------------- batched weight convert: 5 tensors via blockIdx.y ----------------
__global__ void cvt_w5(const float* __restrict__ linW,
                       const float* __restrict__ Wls, const float* __restrict__ Wrs,
                       const float* __restrict__ Wlm, const float* __restrict__ Wrm,
                       ushort* olinW, ushort* oWls, ushort* oWrs, ushort* oWlm, ushort* oWrm) {
  const float* in; ushort* out; int n4;
  switch (blockIdx.y) {
    case 0: in = linW; out = olinW; n4 = H * FIN / 4; break;
    case 1: in = Wls;  out = oWls;  n4 = NLAYERS * H * H / 4; break;
    case 2: in = Wrs;  out = oWrs;  n4 = NLAYERS * H * H / 4; break;
    case 3: in = Wlm;  out = oWlm;  n4 = NLAYERS * H * H / 4; break;
    default: in = Wrm; out = oWrm;  n4 = NLAYERS * H * H / 4; break;
  }
  int i = blockIdx.x * blockDim.x + threadIdx.x;
  if (i >= n4) return;
  float4 v = ((const float4*)in)[i];
  ushort4 o;
  o.x = f2b(v.x); o.y = f2b(v.y); o.z = f2b(v.z); o.w = f2b(v.w);
  ((ushort4*)out)[i] = o;
}

// ---------------- encoder (r6 known-best form) ----------------
__global__ __launch_bounds__(64) void encoder_mfma(
    const float* __restrict__ A, const ushort* __restrict__ Wb,
    const float* __restrict__ bias, const float* __restrict__ memb,
    ushort* __restrict__ C)
{
  int lane = threadIdx.x;
  int rowbase = blockIdx.x * 16;
  int t = lane >> 4, fr = lane & 15;
  f32x4 acc[8];
  #pragma unroll
  for (int c = 0; c < 8; ++c)
    #pragma unroll
    for (int q = 0; q < 4; ++q) acc[c][q] = 0.f;

  int arow = rowbase + fr;
  const float* Abase = A + (long)arow * FIN + t * 8;

  for (int k0 = 0; k0 < FIN; k0 += 32) {
    bf16x8 af, bfm[8];
    {
      const float* pp = Abase + k0;
      float4 v0 = *(const float4*)pp;
      float4 v1 = *(const float4*)(pp + 4);
      ushort tmp[8];
      tmp[0] = f2b(v0.x); tmp[1] = f2b(v0.y); tmp[2] = f2b(v0.z); tmp[3] = f2b(v0.w);
      tmp[4] = f2b(v1.x); tmp[5] = f2b(v1.y); tmp[6] = f2b(v1.z); tmp[7] = f2b(v1.w);
      af = *(bf16x8*)tmp;
    }
    #pragma unroll
    for (int cc = 0; cc < 8; ++cc) {
      int col = cc * 16 + fr;
      bfm[cc] = *(const bf16x8*)(Wb + (long)col * FIN + k0 + t * 8);
    }
    #pragma unroll
    for (int cc = 0; cc < 8; ++cc)
      acc[cc] = __builtin_amdgcn_mfma_f32_16x16x32_bf16(af, bfm[cc], acc[cc], 0, 0, 0);
  }
  #pragma unroll
  for (int cc = 0; cc < 8; ++cc)
    #pragma unroll
    for (int q = 0; q < 4; ++q) {
      int row = rowbase + t * 4 + q;
      int col = cc * 16 + fr;
      float v = acc[cc][q] + bias[col] + memb[(long)row * H + col];
      C[(long)row * H + col] = f2b(v);
    }
}

// ---------------- merged fused layer: 4-rows-per-instruction gather ----------------
// One wave per 16-row tile. Groups of 4 edges (same dst row, padded with -1).
// One load instruction covers 4 neighbor rows (1 KB). Ping-pong 2x4-group banks
// -> up to 8 KB in flight per wave. Run-length flush on row change (uniform),
// cross-lane reduce via 2x shfl_xor.
__global__ __launch_bounds__(64) void fused_layer2(
    const ushort* __restrict__ xmq, const ushort* __restrict__ xsq,
    const int* __restrict__ offs_f, const int* __restrict__ goff_f,
    const int* __restrict__ pcsr_f, const int* __restrict__ grow_f,
    const int* __restrict__ offs_r, const int* __restrict__ goff_r,
    const int* __restrict__ pcsr_r, const int* __restrict__ grow_r,
    const ushort* __restrict__ Wls, const ushort* __restrict__ Wrs,
    const float* __restrict__ bls,
    const ushort* __restrict__ Wlm, const ushort* __restrict__ Wrm,
    const float* __restrict__ blm,
    ushort* __restrict__ nsq, ushort* __restrict__ nmq, int relu)
{
  __shared__ ushort mtile[16 * 128];   // 4 KB, 16B-slot XOR swizzle
  int side = blockIdx.x >= NBLK;
  int bidx = side ? blockIdx.x - NBLK : blockIdx.x;
  const ushort* xg   = side ? xsq    : xmq;
  const ushort* xs   = side ? xmq    : xsq;
  const int*    offs = side ? offs_r : offs_f;
  const int*    goff = side ? goff_r : goff_f;
  const int*    pcsr = side ? pcsr_r : pcsr_f;
  const int*    grow = side ? grow_r : grow_f;
  const ushort* Wl   = side ? Wlm    : Wls;
  const ushort* Wr   = side ? Wrm    : Wrs;
  const float*  bias = side ? blm    : bls;
  ushort*       Cout = side ? nmq    : nsq;

  int lane = threadIdx.x;
  int ep = lane >> 4;        // edge slot within group (0..3)
  int ch = lane & 15;        // 16-B chunk within row (0..15)
  int rowbase = bidx * 16;

  // self-side A fragments prefetch (independent of gather)
  int t = lane >> 4, fr = lane & 15;
  int srow = rowbase + fr;
  bf16x8 sfrag[4];
  #pragma unroll
  for (int ks = 0; ks < 4; ++ks)
    sfrag[ks] = *(const bf16x8*)(xs + (long)srow * H + (ks * 4 + t) * 8);

  // zero mean tile (deg-0 rows never flushed)
  unsigned* mt32 = (unsigned*)mtile;
  #pragma unroll
  for (int i = 0; i < 16; ++i) mt32[i * 64 + lane] = 0;

  float acc8[8];
  #pragma unroll
  for (int q = 0; q < 8; ++q) acc8[q] = 0.f;
  int cur = -1;

  int gbeg = goff[rowbase], gend = goff[rowbase + 16];
  int gn = gend - gbeg;

#define FLUSH() do {                                                        \
    if (cur >= 0) {                                                         \
      _Pragma("unroll")                                                     \
      for (int q = 0; q < 8; ++q) {                                         \
        acc8[q] += __shfl_xor(acc8[q], 16, 64);                             \
        acc8[q] += __shfl_xor(acc8[q], 32, 64);                             \
      }                                                                     \
      int s0 = offs[cur], e0 = offs[cur + 1];                               \
      float inv = (e0 > s0) ? 1.f / (float)(e0 - s0) : 0.f;                 \
      if (ep == 0) {                                                        \
        ushort tmp[8];                                                      \
        _Pragma("unroll")                                                   \
        for (int q = 0; q < 8; ++q) tmp[q] = f2b(acc8[q] * inv);            \
        int sw = (ch & 8) | ((ch & 7) ^ (cur & 7));                         \
        *(bf16x8*)&mtile[(cur & 15) * 128 + sw * 8] = *(bf16x8*)tmp;        \
      }                                                                     \
      _Pragma("unroll")                                                     \
      for (int q = 0; q < 8; ++q) acc8[q] = 0.f;                            \
    } } while (0)

#define LOADBANK(vv, mm, rr, g0) do {                                       \
    _Pragma("unroll")                                                       \
    for (int k = 0; k < 4; ++k) {                                           \
      int gg = (g0) + k;                                                    \
      int ggs = gg < gend ? gg : gbeg;                                      \
      int si = pcsr[ggs * 4 + ep];                                          \
      mm[k] = si >= 0 ? 1.f : 0.f;                                          \
      long rsafe = si >= 0 ? si : 0;                                        \
      vv[k] = *(const bf16x8*)(xg + rsafe * H + ch * 8);                    \
      rr[k] = grow[ggs];                                                    \
    } } while (0)

#define CONSUMEBANK(vv, mm, rr, g0) do {                                    \
    _Pragma("unroll")                                                       \
    for (int k = 0; k < 4; ++k) {                                           \
      int gg = (g0) + k;                                                    \
      if (gg < gend) {                                                      \
        int rnow = rr[k];                                                   \
        if (rnow != cur) { FLUSH(); cur = rnow; }                           \
        _Pragma("unroll")                                                   \
        for (int q = 0; q < 8; ++q)                                         \
          acc8[q] = fmaf(mm[k], b2f((ushort)vv[k][q]), acc8[q]);            \
      }                                                                     \
    } } while (0)

  if (gn > 0) {
    bf16x8 vA[4], vB[4];
    float mA[4], mB[4];
    int rA[4], rB[4];
    LOADBANK(vA, mA, rA, gbeg);
    for (int base = 0; base < gn; base += 8) {
      LOADBANK(vB, mB, rB, gbeg + base + 4);
      CONSUMEBANK(vA, mA, rA, gbeg + base);
      LOADBANK(vA, mA, rA, gbeg + base + 8);
      CONSUMEBANK(vB, mB, rB, gbeg + base + 4);
    }
    FLUSH();
  }
#undef FLUSH
#undef LOADBANK
#undef CONSUMEBANK

  // ---- GEMM phase: out = mean @ Wl^T + bl + self @ Wr^T ----
  f32x4 acc[8];
  #pragma unroll
  for (int c = 0; c < 8; ++c)
    #pragma unroll
    for (int q = 0; q < 4; ++q) acc[c][q] = 0.f;

  #pragma unroll
  for (int ks = 0; ks < 4; ++ks) {
    int slot = ks * 4 + t;
    int sw = (slot & 8) | ((slot & 7) ^ (fr & 7));
    bf16x8 af = *(const bf16x8*)&mtile[fr * 128 + sw * 8];
    bf16x8 bfm[8];
    #pragma unroll
    for (int cc = 0; cc < 8; ++cc) {
      int col = cc * 16 + fr;
      bfm[cc] = *(const bf16x8*)(Wl + (long)col * H + slot * 8);
    }
    #pragma unroll
    for (int cc = 0; cc < 8; ++cc)
      acc[cc] = __builtin_amdgcn_mfma_f32_16x16x32_bf16(af, bfm[cc], acc[cc], 0, 0, 0);
  }
  #pragma unroll
  for (int ks = 0; ks < 4; ++ks) {
    int slot = ks * 4 + t;
    bf16x8 bfm[8];
    #pragma unroll
    for (int cc = 0; cc < 8; ++cc) {
      int col = cc * 16 + fr;
      bfm[cc] = *(const bf16x8*)(Wr + (long)col * H + slot * 8);
    }
    #pragma unroll
    for (int cc = 0; cc < 8; ++cc)
      acc[cc] = __builtin_amdgcn_mfma_f32_16x16x32_bf16(sfrag[ks], bfm[cc], acc[cc], 0, 0, 0);
  }
  #pragma unroll
  for (int cc = 0; cc < 8; ++cc)
    #pragma unroll
    for (int q = 0; q < 4; ++q) {
      int row = rowbase + t * 4 + q;
      int col = cc * 16 + fr;
      float v = acc[cc][q] + bias[col];
      if (relu) v = fmaxf(v, 0.f);
      Cout[(long)row * H + col] = f2b(v);
    }
}

// ---------------- degree count ----------------
__global__ void deg_count(const int* __restrict__ eidx, int* __restrict__ df, int* __restrict__ dr) {
  int e = blockIdx.x * blockDim.x + threadIdx.x;
  if (e >= NE) return;
  atomicAdd(dr + eidx[e], 1);
  atomicAdd(df + eidx[NE + e], 1);
}

// ---------------- dual exclusive scan: edge offsets AND group offsets ----------------
__global__ __launch_bounds__(1024) void exscan2(
    const int* __restrict__ degf, const int* __restrict__ degr,
    int* __restrict__ offf, int* __restrict__ offr,
    int* __restrict__ gofff, int* __restrict__ goffr)
{
  __shared__ int part[1024];
  const int* deg = blockIdx.x ? degr : degf;
  int* offs = blockIdx.x ? offr : offf;
  int* goffs = blockIdx.x ? goffr : gofff;
  int n = blockIdx.x ? NMQ : NSQ;
  int t = threadIdx.x;
  int chunk = (n + 1023) >> 10;
  int beg = t * chunk, end = beg + chunk;
  if (end > n) end = n;

  // pass 1: edge offsets
  {
    int s = 0;
    for (int i = beg; i < end; ++i) s += deg[i];
    part[t] = s;
    __syncthreads();
    for (int offd = 1; offd < 1024; offd <<= 1) {
      int v = 0;
      if (t >= offd) v = part[t - offd];
      __syncthreads();
      part[t] += v;
      __syncthreads();
    }
    int run = (t == 0) ? 0 : part[t - 1];
    for (int i = beg; i < end; ++i) { offs[i] = run; run += deg[i]; }
    if (t == 1023) offs[n] = part[1023];
  }
  __syncthreads();
  // pass 2: group offsets (ceil(deg/4))
  {
    int s = 0;
    for (int i = beg; i < end; ++i) s += (deg[i] + 3) >> 2;
    part[t] = s;
    __syncthreads();
    for (int offd = 1; offd < 1024; offd <<= 1) {
      int v = 0;
      if (t >= offd) v = part[t - offd];
      __syncthreads();
      part[t] += v;
      __syncthreads();
    }
    int run = (t == 0) ? 0 : part[t - 1];
    for (int i = beg; i < end; ++i) { goffs[i] = run; run += (deg[i] + 3) >> 2; }
    if (t == 1023) goffs[n] = part[1023];
  }
}

// ---------------- padded-group CSR fill ----------------
__global__ void csr_fill(const int* __restrict__ eidx,
                         const int* __restrict__ goff_f, const int* __restrict__ goff_r,
                         int* __restrict__ cur_f, int* __restrict__ cur_r,
                         int* __restrict__ pcsr_f, int* __restrict__ pcsr_r,
                         int* __restrict__ grow_f, int* __restrict__ grow_r) {
  int e = blockIdx.x * blockDim.x + threadIdx.x;
  if (e >= NE) return;
  int s = eidx[e], d = eidx[NE + e];
  int p = atomicAdd(cur_f + d, 1);
  int g = goff_f[d] + (p >> 2);
  pcsr_f[g * 4 + (p & 3)] = s;
  grow_f[g] = d;
  int q = atomicAdd(cur_r + s, 1);
  int g2 = goff_r[s] + (q >> 2);
  pcsr_r[g2 * 4 + (q & 3)] = d;
  grow_r[g2] = s;
}

// ---------------- classifier: one wave per label edge ----------------
__global__ __launch_bounds__(256) void edge_dot_b(
    const ushort* __restrict__ xmq, const ushort* __restrict__ xsq,
    const int* __restrict__ eli, float* __restrict__ out)
{
  int wid = (blockIdx.x << 2) + (threadIdx.x >> 6);
  int lane = threadIdx.x & 63;
  if (wid >= NEL) return;
  int a = eli[wid], b = eli[NEL + wid];
  unsigned xa = ((const unsigned*)xmq)[(long)a * 64 + lane];
  unsigned xb = ((const unsigned*)xsq)[(long)b * 64 + lane];
  float p = b2f((ushort)(xa & 0xffff)) * b2f((ushort)(xb & 0xffff))
          + b2f((ushort)(xa >> 16))    * b2f((ushort)(xb >> 16));
  #pragma unroll
  for (int off = 32; off; off >>= 1) p += __shfl_down(p, off, 64);
  if (lane == 0) out[wid] = p;
}

extern "C" void kernel_launch(void* const* d_in, const int* in_sizes, int n_in,
                              void* d_out, int out_size, void* d_ws, size_t ws_size,
                              hipStream_t stream) {
  (void)in_sizes; (void)n_in; (void)out_size; (void)ws_size;
  const float* sq_x      = (const float*)d_in[2];
  const int*   eidx      = (const int*)d_in[3];
  const int*   eli       = (const int*)d_in[4];
  const float* user_emb  = (const float*)d_in[5];
  const float* movie_emb = (const float*)d_in[6];
  const float* lin_W     = (const float*)d_in[7];
  const float* lin_b     = (const float*)d_in[8];
  const float* Wl_s      = (const float*)d_in[9];
  const float* bl_s      = (const float*)d_in[10];
  const float* Wr_s      = (const float*)d_in[11];
  const float* Wl_m      = (const float*)d_in[12];
  const float* bl_m      = (const float*)d_in[13];
  const float* Wr_m      = (const float*)d_in[14];
  float* out = (float*)d_out;

  char* ws = (char*)d_ws;
  size_t off = 0;
  auto alloc = [&](size_t bytes) {
    char* p = ws + off;
    off += (bytes + 255) & ~(size_t)255;
    return p;
  };
  ushort* xmq_a = (ushort*)alloc((size_t)NMQ * H * 2);
  ushort* xmq_b = (ushort*)alloc((size_t)NMQ * H * 2);
  ushort* xsq_a = (ushort*)alloc((size_t)NSQ * H * 2);
  ushort* xsq_b = (ushort*)alloc((size_t)NSQ * H * 2);
  ushort* linWb = (ushort*)alloc((size_t)H * FIN * 2);
  ushort* Wlsb  = (ushort*)alloc((size_t)NLAYERS * H * H * 2);
  ushort* Wrsb  = (ushort*)alloc((size_t)NLAYERS * H * H * 2);
  ushort* Wlmb  = (ushort*)alloc((size_t)NLAYERS * H * H * 2);
  ushort* Wrmb  = (ushort*)alloc((size_t)NLAYERS * H * H * 2);
  int* deg_f  = (int*)alloc((size_t)NSQ * 4);
  int* deg_r  = (int*)alloc((size_t)NMQ * 4);
  int* cur_f  = (int*)alloc((size_t)NSQ * 4);
  int* cur_r  = (int*)alloc((size_t)NMQ * 4);
  int* offs_f = (int*)alloc((size_t)(NSQ + 1) * 4);
  int* offs_r = (int*)alloc((size_t)(NMQ + 1) * 4);
  int* goff_f = (int*)alloc((size_t)(NSQ + 1) * 4);
  int* goff_r = (int*)alloc((size_t)(NMQ + 1) * 4);
  int* pcsr_f = (int*)alloc((size_t)PCMAX * 4);
  int* pcsr_r = (int*)alloc((size_t)PCMAX * 4);
  int* grow_f = (int*)alloc((size_t)NGMAX * 4);
  int* grow_r = (int*)alloc((size_t)NGMAX * 4);

  hipMemsetAsync(deg_f, 0, (char*)offs_f - (char*)deg_f, stream);     // deg+cur zeroed
  hipMemsetAsync(pcsr_f, 0xFF, (char*)grow_f - (char*)pcsr_f, stream); // pcsr = -1

  cvt_bf16<<<(NMQ * H / 4 + 255) / 256, 256, 0, stream>>>(user_emb, xmq_a, NMQ * H / 4);
  cvt_w5<<<dim3((H * FIN / 4 + 255) / 256, 5), 256, 0, stream>>>(
      lin_W, Wl_s, Wr_s, Wl_m, Wr_m, linWb, Wlsb, Wrsb, Wlmb, Wrmb);

  encoder_mfma<<<NSQ / 16, 64, 0, stream>>>(sq_x, linWb, lin_b, movie_emb, xsq_a);
  deg_count<<<(NE + 255) / 256, 256, 0, stream>>>(eidx, deg_f, deg_r);
  exscan2<<<2, 1024, 0, stream>>>(deg_f, deg_r, offs_f, offs_r, goff_f, goff_r);
  csr_fill<<<(NE + 255) / 256, 256, 0, stream>>>(eidx, goff_f, goff_r, cur_f, cur_r,
                                                 pcsr_f, pcsr_r, grow_f, grow_r);

  ushort *cm = xmq_a, *cs = xsq_a, *nm = xmq_b, *ns = xsq_b;
  for (int l = 0; l < NLAYERS; ++l) {
    fused_layer2<<<2 * NBLK, 64, 0, stream>>>(cm, cs,
        offs_f, goff_f, pcsr_f, grow_f,
        offs_r, goff_r, pcsr_r, grow_r,
        Wlsb + (size_t)l * H * H, Wrsb + (size_t)l * H * H, bl_s + (size_t)l * H,
        Wlmb + (size_t)l * H * H, Wrmb + (size_t)l * H * H, bl_m + (size_t)l * H,
        ns, nm, l == 0);
    ushort* t;
    t = cm; cm = nm; nm = t;
    t = cs; cs = ns; ns = t;
  }
  edge_dot_b<<<(NEL + 3) / 4, 256, 0, stream>>>(cm, cs, eli, out);
}

// Round 15
// 681.853 us; speedup vs baseline: 1.1434x; 1.1199x over previous
//
#include <hip/hip_runtime.h>

#define H    128
#define NMQ  50000
#define NSQ  50000
#define NE   600000
#define NEL  200000
#define FIN  768
#define NLAYERS 4
#define NBLK (NSQ / 16)   // 16-row tiles per side

typedef __attribute__((ext_vector_type(8))) short bf16x8;
typedef __attribute__((ext_vector_type(4))) float f32x4;

__device__ inline ushort f2b(float f) {
  unsigned u = __float_as_uint(f);
  u = (u + 0x7FFFu + ((u >> 16) & 1u)) >> 16;
  return (ushort)u;
}
__device__ inline float b2f(ushort h) { return __uint_as_float((unsigned)h << 16); }

// ---------------- fp32 -> bf16 convert (n divisible by 4) ----------------
__global__ void cvt_bf16(const float* __restrict__ in, ushort* __restrict__ out, int n4) {
  int i = blockIdx.x * blockDim.x + threadIdx.x;
  if (i >= n4) return;
  float4 v = ((const float4*)in)[i];
  ushort4 o;
  o.x = f2b(v.x); o.y = f2b(v.y); o.z = f2b(v.z); o.w = f2b(v.w);
  ((ushort4*)out)[i] = o;
}

// ---------------- batched weight convert: 5 tensors via blockIdx.y ----------------
__global__ void cvt_w5(const float* __restrict__ linW,
                       const float* __restrict__ Wls, const float* __restrict__ Wrs,
                       const float* __restrict__ Wlm, const float* __restrict__ Wrm,
                       ushort* olinW, ushort* oWls, ushort* oWrs, ushort* oWlm, ushort* oWrm) {
  const float* in; ushort* out; int n4;
  switch (blockIdx.y) {
    case 0: in = linW; out = olinW; n4 = H * FIN / 4; break;
    case 1: in = Wls;  out = oWls;  n4 = NLAYERS * H * H / 4; break;
    case 2: in = Wrs;  out = oWrs;  n4 = NLAYERS * H * H / 4; break;
    case 3: in = Wlm;  out = oWlm;  n4 = NLAYERS * H * H / 4; break;
    default: in = Wrm; out = oWrm;  n4 = NLAYERS * H * H / 4; break;
  }
  int i = blockIdx.x * blockDim.x + threadIdx.x;
  if (i >= n4) return;
  float4 v = ((const float4*)in)[i];
  ushort4 o;
  o.x = f2b(v.x); o.y = f2b(v.y); o.z = f2b(v.z); o.w = f2b(v.w);
  ((ushort4*)out)[i] = o;
}

// ---------------- encoder: x_sq = bf16(sq_x @ lin_W^T + lin_b + movie_emb) ----------------
// One wave per 16 rows (r6 known-best form).
__global__ __launch_bounds__(64) void encoder_mfma(
    const float* __restrict__ A, const ushort* __restrict__ Wb,
    const float* __restrict__ bias, const float* __restrict__ memb,
    ushort* __restrict__ C)
{
  int lane = threadIdx.x;
  int rowbase = blockIdx.x * 16;
  int t = lane >> 4, fr = lane & 15;
  f32x4 acc[8];
  #pragma unroll
  for (int c = 0; c < 8; ++c)
    #pragma unroll
    for (int q = 0; q < 4; ++q) acc[c][q] = 0.f;

  int arow = rowbase + fr;           // 50000 % 16 == 0
  const float* Abase = A + (long)arow * FIN + t * 8;

  for (int k0 = 0; k0 < FIN; k0 += 32) {
    bf16x8 af, bfm[8];
    {
      const float* p = Abase + k0;
      float4 v0 = *(const float4*)p;
      float4 v1 = *(const float4*)(p + 4);
      ushort tmp[8];
      tmp[0] = f2b(v0.x); tmp[1] = f2b(v0.y); tmp[2] = f2b(v0.z); tmp[3] = f2b(v0.w);
      tmp[4] = f2b(v1.x); tmp[5] = f2b(v1.y); tmp[6] = f2b(v1.z); tmp[7] = f2b(v1.w);
      af = *(bf16x8*)tmp;
    }
    #pragma unroll
    for (int cc = 0; cc < 8; ++cc) {
      int col = cc * 16 + fr;
      bfm[cc] = *(const bf16x8*)(Wb + (long)col * FIN + k0 + t * 8);
    }
    #pragma unroll
    for (int cc = 0; cc < 8; ++cc)
      acc[cc] = __builtin_amdgcn_mfma_f32_16x16x32_bf16(af, bfm[cc], acc[cc], 0, 0, 0);
  }
  #pragma unroll
  for (int cc = 0; cc < 8; ++cc)
    #pragma unroll
    for (int q = 0; q < 4; ++q) {
      int row = rowbase + t * 4 + q;
      int col = cc * 16 + fr;
      float v = acc[cc][q] + bias[col] + memb[(long)row * H + col];
      C[(long)row * H + col] = f2b(v);
    }
}

// ---------------- merged both-sides fused SpMM-mean + SAGE GEMM (r9 form) ----------------
__global__ __launch_bounds__(64) void fused_layer2(
    const ushort* __restrict__ xmq, const ushort* __restrict__ xsq,
    const int* __restrict__ offs_f, const int* __restrict__ csr_f,
    const int* __restrict__ offs_r, const int* __restrict__ csr_r,
    const ushort* __restrict__ Wls, const ushort* __restrict__ Wrs,
    const float* __restrict__ bls,
    const ushort* __restrict__ Wlm, const ushort* __restrict__ Wrm,
    const float* __restrict__ blm,
    ushort* __restrict__ nsq, ushort* __restrict__ nmq, int relu)
{
  __shared__ ushort mtile[16 * 128];  // 4 KB, 16B-slot XOR swizzle
  int side = blockIdx.x >= NBLK;
  int bidx = side ? blockIdx.x - NBLK : blockIdx.x;
  const ushort* xg   = side ? xsq    : xmq;
  const ushort* xs   = side ? xmq    : xsq;
  const int*    offs = side ? offs_r : offs_f;
  const int*    csr  = side ? csr_r  : csr_f;
  const ushort* Wl   = side ? Wlm    : Wls;
  const ushort* Wr   = side ? Wrm    : Wrs;
  const float*  bias = side ? blm    : bls;
  ushort*       Cout = side ? nmq    : nsq;

  int lane = threadIdx.x;
  int rowbase = bidx * 16;
  int t = lane >> 4, fr = lane & 15;
  const unsigned* X = (const unsigned*)xg;

  // prefetch self-side A fragments (independent of gather)
  int srow = rowbase + fr;
  bf16x8 sfrag[4];
  #pragma unroll
  for (int ks = 0; ks < 4; ++ks)
    sfrag[ks] = *(const bf16x8*)(xs + (long)srow * H + (ks * 4 + t) * 8);

  // ---- phase 1: means (register gather, 8-deep) ----
  int wslot = lane >> 2;
  unsigned* mt32 = (unsigned*)mtile;
  for (int i = 0; i < 16; ++i) {
    int row = rowbase + i;
    int s = offs[row], e = offs[row + 1];
    float a0 = 0.f, a1 = 0.f;
    int j = s;
    for (; j + 8 <= e; j += 8) {
      long i0 = csr[j], i1 = csr[j+1], i2 = csr[j+2], i3 = csr[j+3];
      long i4 = csr[j+4], i5 = csr[j+5], i6 = csr[j+6], i7 = csr[j+7];
      unsigned x0 = X[i0*64+lane], x1 = X[i1*64+lane], x2 = X[i2*64+lane], x3 = X[i3*64+lane];
      unsigned x4 = X[i4*64+lane], x5 = X[i5*64+lane], x6 = X[i6*64+lane], x7 = X[i7*64+lane];
      a0 += b2f((ushort)(x0 & 0xffff)) + b2f((ushort)(x1 & 0xffff))
          + b2f((ushort)(x2 & 0xffff)) + b2f((ushort)(x3 & 0xffff))
          + b2f((ushort)(x4 & 0xffff)) + b2f((ushort)(x5 & 0xffff))
          + b2f((ushort)(x6 & 0xffff)) + b2f((ushort)(x7 & 0xffff));
      a1 += b2f((ushort)(x0 >> 16)) + b2f((ushort)(x1 >> 16))
          + b2f((ushort)(x2 >> 16)) + b2f((ushort)(x3 >> 16))
          + b2f((ushort)(x4 >> 16)) + b2f((ushort)(x5 >> 16))
          + b2f((ushort)(x6 >> 16)) + b2f((ushort)(x7 >> 16));
    }
    if (j + 4 <= e) {
      long i0 = csr[j], i1 = csr[j+1], i2 = csr[j+2], i3 = csr[j+3];
      unsigned x0 = X[i0*64+lane], x1 = X[i1*64+lane], x2 = X[i2*64+lane], x3 = X[i3*64+lane];
      a0 += b2f((ushort)(x0 & 0xffff)) + b2f((ushort)(x1 & 0xffff))
          + b2f((ushort)(x2 & 0xffff)) + b2f((ushort)(x3 & 0xffff));
      a1 += b2f((ushort)(x0 >> 16)) + b2f((ushort)(x1 >> 16))
          + b2f((ushort)(x2 >> 16)) + b2f((ushort)(x3 >> 16));
      j += 4;
    }
    for (; j < e; ++j) {
      unsigned x = X[(long)csr[j] * 64 + lane];
      a0 += b2f((ushort)(x & 0xffff));
      a1 += b2f((ushort)(x >> 16));
    }
    float inv = (e > s) ? 1.f / (float)(e - s) : 0.f;
    a0 *= inv; a1 *= inv;
    int sw = (wslot & 8) | ((wslot & 7) ^ (i & 7));
    mt32[i * 64 + sw * 4 + (lane & 3)] = (unsigned)f2b(a0) | ((unsigned)f2b(a1) << 16);
  }
  // wave-local LDS: no barrier needed (one wave per block)

  // ---- phase 2: GEMM ----
  f32x4 acc[8];
  #pragma unroll
  for (int c = 0; c < 8; ++c)
    #pragma unroll
    for (int q = 0; q < 4; ++q) acc[c][q] = 0.f;

  // mean side (A from LDS), K = 128
  #pragma unroll
  for (int ks = 0; ks < 4; ++ks) {
    int slot = ks * 4 + t;
    int sw = (slot & 8) | ((slot & 7) ^ (fr & 7));
    bf16x8 af = *(const bf16x8*)&mtile[fr * 128 + sw * 8];
    bf16x8 bfm[8];
    #pragma unroll
    for (int cc = 0; cc < 8; ++cc) {
      int col = cc * 16 + fr;
      bfm[cc] = *(const bf16x8*)(Wl + (long)col * H + slot * 8);
    }
    #pragma unroll
    for (int cc = 0; cc < 8; ++cc)
      acc[cc] = __builtin_amdgcn_mfma_f32_16x16x32_bf16(af, bfm[cc], acc[cc], 0, 0, 0);
  }
  // self side (A prefetched in registers), K = 128
  #pragma unroll
  for (int ks = 0; ks < 4; ++ks) {
    int slot = ks * 4 + t;
    bf16x8 bfm[8];
    #pragma unroll
    for (int cc = 0; cc < 8; ++cc) {
      int col = cc * 16 + fr;
      bfm[cc] = *(const bf16x8*)(Wr + (long)col * H + slot * 8);
    }
    #pragma unroll
    for (int cc = 0; cc < 8; ++cc)
      acc[cc] = __builtin_amdgcn_mfma_f32_16x16x32_bf16(sfrag[ks], bfm[cc], acc[cc], 0, 0, 0);
  }
  // epilogue
  #pragma unroll
  for (int cc = 0; cc < 8; ++cc)
    #pragma unroll
    for (int q = 0; q < 4; ++q) {
      int row = rowbase + t * 4 + q;
      int col = cc * 16 + fr;
      float v = acc[cc][q] + bias[col];
      if (relu) v = fmaxf(v, 0.f);
      Cout[(long)row * H + col] = f2b(v);
    }
}

// ---------------- degree count ----------------
__global__ void deg_count(const int* __restrict__ eidx, int* __restrict__ df, int* __restrict__ dr) {
  int e = blockIdx.x * blockDim.x + threadIdx.x;
  if (e >= NE) return;
  atomicAdd(dr + eidx[e], 1);
  atomicAdd(df + eidx[NE + e], 1);
}

// ---------------- coalesced dual exclusive scan: block 0 -> fwd, block 1 -> rev ----------------
// Tile-wise: wave shfl-scan (6 steps) + LDS wave-total scan + running carry.
__global__ __launch_bounds__(1024) void exscan2(
    const int* __restrict__ degf, const int* __restrict__ degr,
    int* __restrict__ offf, int* __restrict__ offr)
{
  __shared__ int wtot[16], wpre[17];
  const int* deg = blockIdx.x ? degr : degf;
  int* offs = blockIdx.x ? offr : offf;
  int n = blockIdx.x ? NMQ : NSQ;
  int tid = threadIdx.x, wid = tid >> 6, lane = tid & 63;
  int carry = 0;
  for (int base = 0; base < n; base += 1024) {
    int i = base + tid;
    int d = (i < n) ? deg[i] : 0;
    int v = d;
    #pragma unroll
    for (int s = 1; s < 64; s <<= 1) {
      int tv = __shfl_up(v, s, 64);
      if (lane >= s) v += tv;
    }
    if (lane == 63) wtot[wid] = v;
    __syncthreads();
    if (tid == 0) {
      int run = 0;
      #pragma unroll
      for (int w = 0; w < 16; ++w) { wpre[w] = run; run += wtot[w]; }
      wpre[16] = run;
    }
    __syncthreads();
    if (i < n) offs[i] = carry + wpre[wid] + v - d;
    carry += wpre[16];
  }
  if (tid == 0) offs[n] = carry;
}

// ---------------- CSR fill ----------------
__global__ void csr_fill(const int* __restrict__ eidx,
                         const int* __restrict__ offs_f, const int* __restrict__ offs_r,
                         int* __restrict__ cur_f, int* __restrict__ cur_r,
                         int* __restrict__ csr_f, int* __restrict__ csr_r) {
  int e = blockIdx.x * blockDim.x + threadIdx.x;
  if (e >= NE) return;
  int s = eidx[e], d = eidx[NE + e];
  int p = atomicAdd(cur_f + d, 1); csr_f[offs_f[d] + p] = s;
  int q = atomicAdd(cur_r + s, 1); csr_r[offs_r[s] + q] = d;
}

// ---------------- classifier: one wave per label edge ----------------
__global__ __launch_bounds__(256) void edge_dot_b(
    const ushort* __restrict__ xmq, const ushort* __restrict__ xsq,
    const int* __restrict__ eli, float* __restrict__ out)
{
  int wid = (blockIdx.x << 2) + (threadIdx.x >> 6);
  int lane = threadIdx.x & 63;
  if (wid >= NEL) return;
  int a = eli[wid], b = eli[NEL + wid];
  unsigned xa = ((const unsigned*)xmq)[(long)a * 64 + lane];
  unsigned xb = ((const unsigned*)xsq)[(long)b * 64 + lane];
  float p = b2f((ushort)(xa & 0xffff)) * b2f((ushort)(xb & 0xffff))
          + b2f((ushort)(xa >> 16))    * b2f((ushort)(xb >> 16));
  #pragma unroll
  for (int off = 32; off; off >>= 1) p += __shfl_down(p, off, 64);
  if (lane == 0) out[wid] = p;
}

extern "C" void kernel_launch(void* const* d_in, const int* in_sizes, int n_in,
                              void* d_out, int out_size, void* d_ws, size_t ws_size,
                              hipStream_t stream) {
  (void)in_sizes; (void)n_in; (void)out_size; (void)ws_size;
  // d_in[0]=mq_node_id (arange, unused), d_in[1]=sq_node_id (arange, unused)
  const float* sq_x      = (const float*)d_in[2];
  const int*   eidx      = (const int*)d_in[3];
  const int*   eli       = (const int*)d_in[4];
  const float* user_emb  = (const float*)d_in[5];
  const float* movie_emb = (const float*)d_in[6];
  const float* lin_W     = (const float*)d_in[7];
  const float* lin_b     = (const float*)d_in[8];
  const float* Wl_s      = (const float*)d_in[9];
  const float* bl_s      = (const float*)d_in[10];
  const float* Wr_s      = (const float*)d_in[11];
  const float* Wl_m      = (const float*)d_in[12];
  const float* bl_m      = (const float*)d_in[13];
  const float* Wr_m      = (const float*)d_in[14];
  float* out = (float*)d_out;

  char* ws = (char*)d_ws;
  size_t off = 0;
  auto alloc = [&](size_t bytes) {
    char* p = ws + off;
    off += (bytes + 255) & ~(size_t)255;
    return p;
  };
  ushort* xmq_a = (ushort*)alloc((size_t)NMQ * H * 2);
  ushort* xmq_b = (ushort*)alloc((size_t)NMQ * H * 2);
  ushort* xsq_a = (ushort*)alloc((size_t)NSQ * H * 2);
  ushort* xsq_b = (ushort*)alloc((size_t)NSQ * H * 2);
  ushort* linWb = (ushort*)alloc((size_t)H * FIN * 2);
  ushort* Wlsb  = (ushort*)alloc((size_t)NLAYERS * H * H * 2);
  ushort* Wrsb  = (ushort*)alloc((size_t)NLAYERS * H * H * 2);
  ushort* Wlmb  = (ushort*)alloc((size_t)NLAYERS * H * H * 2);
  ushort* Wrmb  = (ushort*)alloc((size_t)NLAYERS * H * H * 2);
  int* deg_f  = (int*)alloc((size_t)NSQ * 4);
  int* deg_r  = (int*)alloc((size_t)NMQ * 4);
  int* cur_f  = (int*)alloc((size_t)NSQ * 4);
  int* cur_r  = (int*)alloc((size_t)NMQ * 4);
  int* offs_f = (int*)alloc((size_t)(NSQ + 1) * 4);
  int* offs_r = (int*)alloc((size_t)(NMQ + 1) * 4);
  int* csr_f  = (int*)alloc((size_t)NE * 4);
  int* csr_r  = (int*)alloc((size_t)NE * 4);

  hipMemsetAsync(deg_f, 0, (char*)offs_f - (char*)deg_f, stream);

  // conversions (2 launches: embeddings + batched weights)
  cvt_bf16<<<(NMQ * H / 4 + 255) / 256, 256, 0, stream>>>(user_emb, xmq_a, NMQ * H / 4);
  cvt_w5<<<dim3((H * FIN / 4 + 255) / 256, 5), 256, 0, stream>>>(
      lin_W, Wl_s, Wr_s, Wl_m, Wr_m, linWb, Wlsb, Wrsb, Wlmb, Wrmb);

  encoder_mfma<<<NSQ / 16, 64, 0, stream>>>(sq_x, linWb, lin_b, movie_emb, xsq_a);
  deg_count<<<(NE + 255) / 256, 256, 0, stream>>>(eidx, deg_f, deg_r);
  exscan2<<<2, 1024, 0, stream>>>(deg_f, deg_r, offs_f, offs_r);
  csr_fill<<<(NE + 255) / 256, 256, 0, stream>>>(eidx, offs_f, offs_r, cur_f, cur_r, csr_f, csr_r);

  ushort *cm = xmq_a, *cs = xsq_a, *nm = xmq_b, *ns = xsq_b;
  for (int l = 0; l < NLAYERS; ++l) {
    fused_layer2<<<2 * NBLK, 64, 0, stream>>>(cm, cs, offs_f, csr_f, offs_r, csr_r,
        Wlsb + (size_t)l * H * H, Wrsb + (size_t)l * H * H, bl_s + (size_t)l * H,
        Wlmb + (size_t)l * H * H, Wrmb + (size_t)l * H * H, bl_m + (size_t)l * H,
        ns, nm, l == 0);
    ushort* t;
    t = cm; cm = nm; nm = t;
    t = cs; cs = ns; ns = t;
  }
  edge_dot_b<<<(NEL + 3) / 4, 256, 0, stream>>>(cm, cs, eli, out);
}